// Round 16
// baseline (468.640 us; speedup 1.0000x reference)
//
#include <hip/hip_runtime.h>
#include <hip/hip_bf16.h>
#include <hip/hip_cooperative_groups.h>
#include <math.h>

namespace cg = cooperative_groups;

#define SZ 48
#define NC 2304          // SIZE*SIZE
#define BB 4
#define DD 32
#define NH 4
#define HD 8
#define NL 2
#define DFF 2048
#define KSP 2
#define NQB (NC/16)            // 144
#define JOBS (BB*NH*NQB*KSP)   // 4608 attention wave-jobs
#define NTB  ((BB*NC)/16)      // 576 token/tail jobs
#define CBLK 576               // cooperative grid (each wave: 2 attn jobs)

#define QSCALE 0.51011784f     // (1/sqrt(8)) * log2(e)

// ws layout in floats
#define OFF_TABLE 16
#define OFF_X   256
#define OFF_QB  (OFF_X   + BB*NC*DD)
#define OFF_KB  (OFF_QB  + (BB*NC*DD)/2)
#define OFF_VT  (OFF_KB  + (BB*NC*DD)/2)
#define OFF_OP  (OFF_VT  + (BB*NC*DD)/2)
#define OFF_RS  (OFF_OP  + JOBS*128)
#define OFF_W1B (OFF_RS  + JOBS*16)
#define OFF_W2B (OFF_W1B + (NL*DFF*DD)/2)
#define OFF_WQB (OFF_W2B + (NL*DFF*DD)/2)
#define OFF_WOB (OFF_WQB + (NL*96*DD)/2)

typedef __bf16 bf16x8 __attribute__((ext_vector_type(8)));
typedef __bf16 bf16x4 __attribute__((ext_vector_type(4)));
typedef float f32x4 __attribute__((ext_vector_type(4)));

__device__ __forceinline__ float gelu_exact(float x) {
    return 0.5f * x * (1.0f + erff(x * 0.7071067811865476f));
}
__device__ __forceinline__ float exp2_raw(float x) {
    float r;
    asm("v_exp_f32 %0, %1" : "=v"(r) : "v"(x));
    return r;
}

// ================= shared device bodies (used by mega AND fallback kernels)

// ---- setup block: agent argmax + 8-combo MLP table (one 256-thread block)
__device__ __forceinline__ void setup_body(const float* obs,
    const float* w1, const float* b1, const float* w2, const float* b2,
    const float* w3, const float* b3, const float* w4, const float* b4,
    float* ws, unsigned char* smem, int tid)
{
    int* s_agent = (int*)smem;
    float (*h1)[64]  = (float(*)[64]) (smem + 16);
    float (*h2)[128] = (float(*)[128])(smem + 16 + 2048);
    float (*h3)[64]  = (float(*)[64]) (smem + 16 + 2048 + 4096);
    if (tid == 0) *s_agent = 0;
    __syncthreads();
    for (int n = tid; n < NC; n += 256)
        if (obs[n] > 0.5f) atomicMax(s_agent, n);
    __syncthreads();
    int a = *s_agent;
    if (tid < 4) {
        const int di[4] = {-1, 1, 0, 0};
        const int dj[4] = {0, 0, -1, 1};
        int ai = a / SZ, aj = a % SZ;
        int ni = ai + di[tid], nj = aj + dj[tid];
        bool inb = (ni >= 0) && (ni < SZ) && (nj >= 0) && (nj < SZ);
        int nic = min(max(ni, 0), SZ - 1), njc = min(max(nj, 0), SZ - 1);
        bool ok = inb && (obs[2 * NC + nic * SZ + njc] == 0.0f);
        int ti = ok ? nic : ai, tj = ok ? njc : aj;
        ((int*)ws)[tid] = ti * SZ + tj;
    }
    for (int it = 0; it < 2; ++it) {
        int idx = tid + it * 256;
        int c = idx >> 6, j = idx & 63;
        float in0 = (float)((c >> 2) & 1);
        float in1 = (float)((c >> 1) & 1);
        float in2 = (float)(c & 1);
        float v = b1[j] + w1[j*3+0]*in0 + w1[j*3+1]*in1 + w1[j*3+2]*in2;
        h1[c][j] = gelu_exact(v);
    }
    __syncthreads();
    for (int it = 0; it < 4; ++it) {
        int idx = tid + it * 256;
        int c = idx >> 7, j = idx & 127;
        float v = b2[j];
        for (int k = 0; k < 64; ++k) v += w2[j*64+k] * h1[c][k];
        h2[c][j] = gelu_exact(v);
    }
    __syncthreads();
    for (int it = 0; it < 2; ++it) {
        int idx = tid + it * 256;
        int c = idx >> 6, j = idx & 63;
        float v = b3[j];
        for (int k = 0; k < 128; ++k) v += w3[j*128+k] * h2[c][k];
        h3[c][j] = gelu_exact(v);
    }
    __syncthreads();
    if (tid < 128) {
        int c = tid >> 4, j = tid & 15;
        float v = b4[j];
        for (int k = 0; k < 64; ++k) v += w4[j*64+k] * h3[c][k];
        ws[OFF_TABLE + c*16 + j] = v;
    }
}

// ---- one 16-token token-build + layer-0 qkv job (tab/apos preloaded+synced)
__device__ __forceinline__ void tokens_job(const float* obs, const float* abs_emb,
    const float* rel_w, const float* rel_b, const float* ang_w, const float* ang_b,
    const float* nbr_w, const float* nbr_b,
    const float* tab, const int* apos, float* X,
    const __bf16* Wq, const float* qbias,
    __bf16* Qb, __bf16* Kb, __bf16* Vt, int gw, int lo, int kg)
{
    const f32x4 zero = {0, 0, 0, 0};
    int t0 = gw * 16;
    int b = t0 / NC;
    int n = (t0 % NC) + lo;
    int ap = apos[b];
    const float* goal = obs + NC;
    const float* wall = obs + 2 * NC;
    int i = n / SZ, j = n % SZ;

    float val[8];
    if (kg < 2) {
        int c0 = ((n == ap) ? 4 : 0) | ((goal[n] > 0.5f) ? 2 : 0) | ((wall[n] > 0.5f) ? 1 : 0);
        #pragma unroll
        for (int c = 0; c < 8; ++c) val[c] = tab[c0*16 + kg*8 + c];
    } else if (kg == 2) {
        #pragma unroll
        for (int o = 0; o < 4; ++o) val[o] = abs_emb[n*4 + o];
        int ar = ap / SZ, ac = ap % SZ;
        const float scc = 2.0f / (SZ - 1);
        float dr = (float)(ar - i) * scc;
        float dc = (float)(ac - j) * scc;
        #pragma unroll
        for (int o = 0; o < 4; ++o)
            val[4 + o] = rel_b[o] + rel_w[o*2+0]*dr + rel_w[o*2+1]*dc;
    } else {
        int ar = ap / SZ, ac = ap % SZ;
        const float scc = 2.0f / (SZ - 1);
        float dr = (float)(ar - i) * scc;
        float dc = (float)(ac - j) * scc;
        float ang = atan2f(dc, dr);
        float sa = sinf(ang), ca = cosf(ang);
        #pragma unroll
        for (int o = 0; o < 4; ++o)
            val[o] = ang_b[o] + ang_w[o*2+0]*sa + ang_w[o*2+1]*ca;
        int nb[4];
        nb[0] = (i > 0)      ? n - SZ : n;
        nb[1] = (i < SZ - 1) ? n + SZ : n;
        nb[2] = (j > 0)      ? n - 1  : n;
        nb[3] = (j < SZ - 1) ? n + 1  : n;
        float navg[16];
        #pragma unroll
        for (int c = 0; c < 16; ++c) navg[c] = 0.f;
        #pragma unroll
        for (int q = 0; q < 4; ++q) {
            int m = nb[q];
            int cq = ((m == ap) ? 4 : 0) | ((goal[m] > 0.5f) ? 2 : 0) | ((wall[m] > 0.5f) ? 1 : 0);
            #pragma unroll
            for (int c = 0; c < 16; ++c) navg[c] += tab[cq*16 + c];
        }
        #pragma unroll
        for (int o = 0; o < 4; ++o) {
            float v = nbr_b[o];
            #pragma unroll
            for (int c = 0; c < 16; ++c) v += nbr_w[o*16 + c] * (navg[c] * 0.25f);
            val[4 + o] = v;
        }
    }
    bf16x8 a;
    #pragma unroll
    for (int jj = 0; jj < 8; ++jj) {
        X[(size_t)(t0 + lo) * DD + kg * 8 + jj] = val[jj];
        a[jj] = (__bf16)val[jj];
    }
    f32x4 acc[6];
    #pragma unroll
    for (int nn = 0; nn < 6; ++nn) {
        bf16x8 bf = *reinterpret_cast<const bf16x8*>(Wq + (size_t)(nn * 16 + lo) * DD + kg * 8);
        acc[nn] = __builtin_amdgcn_mfma_f32_16x16x32_bf16(a, bf, zero, 0, 0, 0);
    }
    #pragma unroll
    for (int nn = 0; nn < 6; ++nn) {
        int o = nn * 16 + lo;
        float bi = qbias[o];
        int part = o >> 5, oo = o & 31;
        int h = oo >> 3, dd = oo & 7;
        size_t bh = (size_t)(b * NH + h);
        #pragma unroll
        for (int r = 0; r < 4; ++r) {
            int t = t0 + kg * 4 + r;
            int tn = t % NC;
            float s = acc[nn][r] + bi;
            if (part == 0)
                Qb[(bh * NC + tn) * HD + dd] = (__bf16)(s * QSCALE);
            else if (part == 1)
                Kb[(bh * NC + tn) * HD + dd] = (__bf16)s;
            else
                Vt[(bh * HD + dd) * NC + tn] = (__bf16)s;
        }
    }
}

// ---- attention job (R10-best body); pl = per-wave 576-elem bf16 LDS region
__device__ __forceinline__ void attn_job(const __bf16* Qb, const __bf16* Kb,
    const __bf16* Vt, float* Op, float* Rs, __bf16* pl, int lo, int kg, int job)
{
    const f32x4 zero = {0, 0, 0, 0};
    int bh  = job / (NQB * KSP);
    int rem = job % (NQB * KSP);
    int qb = rem >> 1, ks = rem & 1;

    bf16x8 qfrag = {};
    if (kg == 0)
        qfrag = *reinterpret_cast<const bf16x8*>(Qb + ((size_t)bh * NC + qb * 16 + lo) * HD);
    int k0base = ks * (NC / KSP);
    bool klane = (kg == 0);
    bool vlane = (lo < 8);

    bf16x8 vinit = {};
    if (lo == 8) {
        #pragma unroll
        for (int jj = 0; jj < 8; ++jj) vinit[jj] = (__bf16)1.0f;
    }

    bf16x8 kf0 = {}, kf1 = {};
    bf16x8 vcur = vinit;
    if (klane) {
        kf0 = *reinterpret_cast<const bf16x8*>(Kb + ((size_t)bh * NC + k0base + lo) * HD);
        kf1 = *reinterpret_cast<const bf16x8*>(Kb + ((size_t)bh * NC + k0base + 16 + lo) * HD);
    }
    if (vlane)
        vcur = *reinterpret_cast<const bf16x8*>(Vt + ((size_t)bh * HD + lo) * NC + k0base + kg * 8);

    f32x4 acc = zero;
    const int NCH = (NC / KSP) / 32;   // 36
    for (int ch = 0; ch < NCH; ++ch) {
        bf16x8 kf0c = kf0, kf1c = kf1, vc = vcur;
        if (ch + 1 < NCH) {
            int k1 = k0base + (ch + 1) * 32;
            if (klane) {
                kf0 = *reinterpret_cast<const bf16x8*>(Kb + ((size_t)bh * NC + k1 + lo) * HD);
                kf1 = *reinterpret_cast<const bf16x8*>(Kb + ((size_t)bh * NC + k1 + 16 + lo) * HD);
            }
            if (vlane)
                vcur = *reinterpret_cast<const bf16x8*>(Vt + ((size_t)bh * HD + lo) * NC + k1 + kg * 8);
        }
        f32x4 s0 = __builtin_amdgcn_mfma_f32_16x16x32_bf16(kf0c, qfrag, zero, 0, 0, 0);
        f32x4 s1 = __builtin_amdgcn_mfma_f32_16x16x32_bf16(kf1c, qfrag, zero, 0, 0, 0);
        bf16x4 p0, p1;
        #pragma unroll
        for (int r = 0; r < 4; ++r) p0[r] = (__bf16)exp2_raw(s0[r]);
        #pragma unroll
        for (int r = 0; r < 4; ++r) p1[r] = (__bf16)exp2_raw(s1[r]);
        *reinterpret_cast<bf16x4*>(pl + lo * 36 + kg * 4)      = p0;
        *reinterpret_cast<bf16x4*>(pl + lo * 36 + 16 + kg * 4) = p1;
        bf16x8 pa = *reinterpret_cast<const bf16x8*>(pl + lo * 36 + kg * 8);
        acc = __builtin_amdgcn_mfma_f32_16x16x32_bf16(pa, vc, acc, 0, 0, 0);
    }
    if (lo < 8) {
        #pragma unroll
        for (int r = 0; r < 4; ++r)
            Op[(size_t)job * 128 + (kg * 4 + r) * 8 + lo] = acc[r];
    } else if (lo == 8) {
        #pragma unroll
        for (int r = 0; r < 4; ++r)
            Rs[(size_t)job * 16 + kg * 4 + r] = acc[r];
    }
}

// ---- layer tail (R12-validated body)
__device__ __forceinline__ void layer_tail(unsigned char* smem,
    float* Xf, const float* Op, const float* Rs,
    const __bf16* Wo, const float* obias,
    const float* g1, const float* bg1,
    const __bf16* w1b, const float* fb1,
    const __bf16* w2b, const float* fb2,
    const float* g2, const float* bg2,
    const __bf16* Wqn, const float* qbn,
    __bf16* Qb, __bf16* Kb, __bf16* Vt,
    float* out, int last, int t0, int w, int l, int lo, int kg)
{
    __bf16* Xl = (__bf16*)smem;                 // 16*40
    __bf16* Hl = (__bf16*)(smem + 1280);        // [4][2][648]
    float*  accred = (float*)(smem + 11648);    // [4][64][16]
    const f32x4 zero = {0, 0, 0, 0};
    int b = t0 / NC, qb = (t0 % NC) >> 4;

    float xr0[4], xr1[4];
    if (w == 0) {
        int jb = ((b * NH + kg) * NQB + qb) * KSP;
        float rs = 0.f;
        float ov[8];
        #pragma unroll
        for (int jj = 0; jj < 8; ++jj) ov[jj] = 0.f;
        #pragma unroll
        for (int s = 0; s < KSP; ++s) {
            rs += Rs[(jb + s) * 16 + lo];
            const float* pp = Op + (size_t)(jb + s) * 128 + lo * 8;
            #pragma unroll
            for (int jj = 0; jj < 8; ++jj) ov[jj] += pp[jj];
        }
        float inv = 1.0f / rs;
        bf16x8 a;
        #pragma unroll
        for (int jj = 0; jj < 8; ++jj) a[jj] = (__bf16)(ov[jj] * inv);
        bf16x8 bf0 = *reinterpret_cast<const bf16x8*>(Wo + (size_t)lo * DD + kg * 8);
        bf16x8 bf1 = *reinterpret_cast<const bf16x8*>(Wo + (size_t)(16 + lo) * DD + kg * 8);
        f32x4 acc0 = __builtin_amdgcn_mfma_f32_16x16x32_bf16(a, bf0, zero, 0, 0, 0);
        f32x4 acc1 = __builtin_amdgcn_mfma_f32_16x16x32_bf16(a, bf1, zero, 0, 0, 0);
        float bi0 = obias[lo], bi1 = obias[16 + lo];
        float gg0 = g1[lo], gg1 = g1[16 + lo];
        float bb0 = bg1[lo], bb1 = bg1[16 + lo];
        #pragma unroll
        for (int r = 0; r < 4; ++r) {
            int t = t0 + kg * 4 + r;
            float y0 = Xf[(size_t)t * DD + lo]      + acc0[r] + bi0;
            float y1 = Xf[(size_t)t * DD + 16 + lo] + acc1[r] + bi1;
            float s = y0 + y1;
            s += __shfl_xor(s, 1, 16); s += __shfl_xor(s, 2, 16);
            s += __shfl_xor(s, 4, 16); s += __shfl_xor(s, 8, 16);
            float mu = s * (1.0f / DD);
            float d0 = y0 - mu, d1 = y1 - mu;
            float v = d0 * d0 + d1 * d1;
            v += __shfl_xor(v, 1, 16); v += __shfl_xor(v, 2, 16);
            v += __shfl_xor(v, 4, 16); v += __shfl_xor(v, 8, 16);
            float linv = 1.0f / sqrtf(v * (1.0f / DD) + 1e-5f);
            xr0[r] = d0 * linv * gg0 + bb0;
            xr1[r] = d1 * linv * gg1 + bb1;
            Xl[(kg * 4 + r) * 40 + lo]      = (__bf16)xr0[r];
            Xl[(kg * 4 + r) * 40 + 16 + lo] = (__bf16)xr1[r];
        }
    }
    __syncthreads();

    bf16x8 a1 = *reinterpret_cast<const bf16x8*>(&Xl[lo * 40 + kg * 8]);
    f32x4 accA0 = zero, accA1 = zero, accB0 = zero, accB1 = zero;
    for (int cc = w * 512; cc < w * 512 + 512; cc += 64) {
        int cA = cc, cB = cc + 32;
        bf16x8 b1A0 = *reinterpret_cast<const bf16x8*>(w1b + (size_t)(cA + lo) * DD + kg*8);
        bf16x8 b1A1 = *reinterpret_cast<const bf16x8*>(w1b + (size_t)(cA + 16 + lo) * DD + kg*8);
        bf16x8 b1B0 = *reinterpret_cast<const bf16x8*>(w1b + (size_t)(cB + lo) * DD + kg*8);
        bf16x8 b1B1 = *reinterpret_cast<const bf16x8*>(w1b + (size_t)(cB + 16 + lo) * DD + kg*8);
        f32x4 c1A0 = __builtin_amdgcn_mfma_f32_16x16x32_bf16(a1, b1A0, zero, 0, 0, 0);
        f32x4 c1A1 = __builtin_amdgcn_mfma_f32_16x16x32_bf16(a1, b1A1, zero, 0, 0, 0);
        f32x4 c1B0 = __builtin_amdgcn_mfma_f32_16x16x32_bf16(a1, b1B0, zero, 0, 0, 0);
        f32x4 c1B1 = __builtin_amdgcn_mfma_f32_16x16x32_bf16(a1, b1B1, zero, 0, 0, 0);
        float bA0 = fb1[cA + lo], bA1 = fb1[cA + 16 + lo];
        float bB0 = fb1[cB + lo], bB1 = fb1[cB + 16 + lo];
        __bf16* h0 = Hl + (w * 2 + 0) * 648;
        __bf16* h1 = Hl + (w * 2 + 1) * 648;
        #pragma unroll
        for (int r = 0; r < 4; ++r) {
            int tok = kg * 4 + r;
            h0[tok*40 + lo]      = (__bf16)fmaxf(c1A0[r] + bA0, 0.f);
            h0[tok*40 + 16 + lo] = (__bf16)fmaxf(c1A1[r] + bA1, 0.f);
            h1[tok*40 + lo]      = (__bf16)fmaxf(c1B0[r] + bB0, 0.f);
            h1[tok*40 + 16 + lo] = (__bf16)fmaxf(c1B1[r] + bB1, 0.f);
        }
        bf16x8 a2A = *reinterpret_cast<const bf16x8*>(&h0[lo*40 + kg*8]);
        bf16x8 a2B = *reinterpret_cast<const bf16x8*>(&h1[lo*40 + kg*8]);
        bf16x8 b2A0 = *reinterpret_cast<const bf16x8*>(w2b + (size_t)lo * DFF + cA + kg*8);
        bf16x8 b2A1 = *reinterpret_cast<const bf16x8*>(w2b + (size_t)(16 + lo) * DFF + cA + kg*8);
        bf16x8 b2B0 = *reinterpret_cast<const bf16x8*>(w2b + (size_t)lo * DFF + cB + kg*8);
        bf16x8 b2B1 = *reinterpret_cast<const bf16x8*>(w2b + (size_t)(16 + lo) * DFF + cB + kg*8);
        accA0 = __builtin_amdgcn_mfma_f32_16x16x32_bf16(a2A, b2A0, accA0, 0, 0, 0);
        accA1 = __builtin_amdgcn_mfma_f32_16x16x32_bf16(a2A, b2A1, accA1, 0, 0, 0);
        accB0 = __builtin_amdgcn_mfma_f32_16x16x32_bf16(a2B, b2B0, accB0, 0, 0, 0);
        accB1 = __builtin_amdgcn_mfma_f32_16x16x32_bf16(a2B, b2B1, accB1, 0, 0, 0);
    }
    float* ar = accred + ((size_t)w * 64 + l) * 16;
    *reinterpret_cast<f32x4*>(ar + 0)  = accA0;
    *reinterpret_cast<f32x4*>(ar + 4)  = accA1;
    *reinterpret_cast<f32x4*>(ar + 8)  = accB0;
    *reinterpret_cast<f32x4*>(ar + 12) = accB1;
    __syncthreads();
    if (w != 0) return;

    accA0 = zero; accA1 = zero; accB0 = zero; accB1 = zero;
    #pragma unroll
    for (int ww = 0; ww < 4; ++ww) {
        const float* br = accred + ((size_t)ww * 64 + l) * 16;
        accA0 += *reinterpret_cast<const f32x4*>(br + 0);
        accA1 += *reinterpret_cast<const f32x4*>(br + 4);
        accB0 += *reinterpret_cast<const f32x4*>(br + 8);
        accB1 += *reinterpret_cast<const f32x4*>(br + 12);
    }
    float b2v0 = fb2[lo], b2v1 = fb2[16 + lo];
    float gg0 = g2[lo], gg1 = g2[16 + lo];
    float bb0 = bg2[lo], bb1 = bg2[16 + lo];
    float s0 = 0.f, s1 = 0.f;
    #pragma unroll
    for (int r = 0; r < 4; ++r) {
        int t = t0 + kg * 4 + r;
        float y0 = xr0[r] + accA0[r] + accB0[r] + b2v0;
        float y1 = xr1[r] + accA1[r] + accB1[r] + b2v1;
        float s = y0 + y1;
        s += __shfl_xor(s, 1, 16); s += __shfl_xor(s, 2, 16);
        s += __shfl_xor(s, 4, 16); s += __shfl_xor(s, 8, 16);
        float mu = s * (1.0f / DD);
        float d0 = y0 - mu, d1 = y1 - mu;
        float v = d0 * d0 + d1 * d1;
        v += __shfl_xor(v, 1, 16); v += __shfl_xor(v, 2, 16);
        v += __shfl_xor(v, 4, 16); v += __shfl_xor(v, 8, 16);
        float linv = 1.0f / sqrtf(v * (1.0f / DD) + 1e-5f);
        float o0 = d0 * linv * gg0 + bb0;
        float o1 = d1 * linv * gg1 + bb1;
        if (!last) {
            Xf[(size_t)t * DD + lo]      = o0;
            Xf[(size_t)t * DD + 16 + lo] = o1;
            Xl[(kg * 4 + r) * 40 + lo]      = (__bf16)o0;
            Xl[(kg * 4 + r) * 40 + 16 + lo] = (__bf16)o1;
        } else {
            s0 += o0;
            s1 += o1;
        }
    }
    if (!last) {
        bf16x8 a = *reinterpret_cast<const bf16x8*>(&Xl[lo * 40 + kg * 8]);
        f32x4 accq[6];
        #pragma unroll
        for (int nn = 0; nn < 6; ++nn) {
            bf16x8 bf = *reinterpret_cast<const bf16x8*>(Wqn + (size_t)(nn * 16 + lo) * DD + kg * 8);
            accq[nn] = __builtin_amdgcn_mfma_f32_16x16x32_bf16(a, bf, zero, 0, 0, 0);
        }
        #pragma unroll
        for (int nn = 0; nn < 6; ++nn) {
            int o = nn * 16 + lo;
            float bi = qbn[o];
            int part = o >> 5, oo = o & 31;
            int h = oo >> 3, dd = oo & 7;
            size_t bh = (size_t)(b * NH + h);
            #pragma unroll
            for (int r = 0; r < 4; ++r) {
                int t = t0 + kg * 4 + r;
                int tn = t % NC;
                float s = accq[nn][r] + bi;
                if (part == 0)
                    Qb[(bh * NC + tn) * HD + dd] = (__bf16)(s * QSCALE);
                else if (part == 1)
                    Kb[(bh * NC + tn) * HD + dd] = (__bf16)s;
                else
                    Vt[(bh * HD + dd) * NC + tn] = (__bf16)s;
            }
        }
    } else {
        s0 += __shfl_xor(s0, 16); s0 += __shfl_xor(s0, 32);
        s1 += __shfl_xor(s1, 16); s1 += __shfl_xor(s1, 32);
        if (l < 16) {
            atomicAdd(out + b * DD + lo,      s0 * (1.0f / NC));
            atomicAdd(out + b * DD + 16 + lo, s1 * (1.0f / NC));
        }
    }
}

// ================= args struct
struct MegaArgs {
    const float *obs;
    const float *mlp_w1, *mlp_b1, *mlp_w2, *mlp_b2, *mlp_w3, *mlp_b3, *mlp_w4, *mlp_b4;
    const float *abs_emb, *rel_w, *rel_b, *ang_w, *ang_b, *nbr_w, *nbr_b;
    const float *attn_in_w, *attn_in_b, *attn_out_w, *attn_out_b;
    const float *ff_w1, *ff_b1, *ff_w2, *ff_b2, *ln1_g, *ln1_b, *ln2_g, *ln2_b;
    float *ws;
    float *out;
};

// ================= the cooperative mega kernel (576 blocks, 3 waves/EU cap)
__global__ void __launch_bounds__(256, 3)
mega(MegaArgs A)
{
    cg::grid_group grid = cg::this_grid();
    __shared__ __align__(16) unsigned char smem[28032];
    int tid = threadIdx.x;
    int w = tid >> 6, l = tid & 63, lo = l & 15, kg = l >> 4;
    int blk = blockIdx.x;

    float* ws = A.ws;
    float* X  = ws + OFF_X;
    __bf16* Qb = (__bf16*)(ws + OFF_QB);
    __bf16* Kb = (__bf16*)(ws + OFF_KB);
    __bf16* Vt = (__bf16*)(ws + OFF_VT);
    float* Op = ws + OFF_OP;
    float* Rs = ws + OFF_RS;
    __bf16* w1b = (__bf16*)(ws + OFF_W1B);
    __bf16* w2b = (__bf16*)(ws + OFF_W2B);
    __bf16* wqb = (__bf16*)(ws + OFF_WQB);
    __bf16* wob = (__bf16*)(ws + OFF_WOB);

    // phase 0: setup + convert + out zero
    if (blk == 0) {
        setup_body(A.obs, A.mlp_w1, A.mlp_b1, A.mlp_w2, A.mlp_b2,
                   A.mlp_w3, A.mlp_b3, A.mlp_w4, A.mlp_b4, ws, smem, tid);
    } else {
        if (blk == 1 && tid < BB * DD) A.out[tid] = 0.f;
        for (int i = (blk - 1) * 256 + tid; i < NL*DFF*DD; i += (CBLK - 1) * 256) {
            w1b[i] = (__bf16)A.ff_w1[i];
            w2b[i] = (__bf16)A.ff_w2[i];
            if (i < NL*96*DD) wqb[i] = (__bf16)A.attn_in_w[i];
            if (i < NL*DD*DD) wob[i] = (__bf16)A.attn_out_w[i];
        }
    }
    grid.sync();

    // phase 1: tokens + layer-0 qkv (576 wave jobs over 2304 slots)
    {
        float* tab = (float*)smem;
        int* apos = (int*)(smem + 512);
        if (tid < 128) tab[tid] = ws[OFF_TABLE + tid];
        if (tid < 4) apos[tid] = ((const int*)ws)[tid];
        __syncthreads();
        int gw = blk * 4 + w;
        if (gw < NTB)
            tokens_job(A.obs, A.abs_emb, A.rel_w, A.rel_b, A.ang_w, A.ang_b,
                       A.nbr_w, A.nbr_b, tab, apos, X, wqb, A.attn_in_b,
                       Qb, Kb, Vt, gw, lo, kg);
    }
    grid.sync();

    // phase 2: attention L0 (each wave does jobs blk*4+w and +2304)
    attn_job(Qb, Kb, Vt, Op, Rs, (__bf16*)smem + w * 576, lo, kg, blk * 4 + w);
    attn_job(Qb, Kb, Vt, Op, Rs, (__bf16*)smem + w * 576, lo, kg, blk * 4 + w + CBLK * 4);
    grid.sync();

    // phase 3: tail L0 (writes layer-1 qkv)
    layer_tail(smem, X, Op, Rs,
        wob, A.attn_out_b, A.ln1_g, A.ln1_b,
        w1b, A.ff_b1, w2b, A.ff_b2, A.ln2_g, A.ln2_b,
        wqb + (size_t)96*DD, A.attn_in_b + 96,
        Qb, Kb, Vt, A.out, 0, blk * 16, w, l, lo, kg);
    grid.sync();

    // phase 4: attention L1
    attn_job(Qb, Kb, Vt, Op, Rs, (__bf16*)smem + w * 576, lo, kg, blk * 4 + w);
    attn_job(Qb, Kb, Vt, Op, Rs, (__bf16*)smem + w * 576, lo, kg, blk * 4 + w + CBLK * 4);
    grid.sync();

    // phase 5: tail L1 + mean
    layer_tail(smem, X, Op, Rs,
        wob + (size_t)DD*DD, A.attn_out_b + DD, A.ln1_g + DD, A.ln1_b + DD,
        w1b + (size_t)DFF*DD, A.ff_b1 + DFF, w2b + (size_t)DD*DFF, A.ff_b2 + DD,
        A.ln2_g + DD, A.ln2_b + DD,
        wqb, A.attn_in_b,
        Qb, Kb, Vt, A.out, 1, blk * 16, w, l, lo, kg);
}

// ================= fallback kernels (R12-proven 6-dispatch path)
__global__ void __launch_bounds__(256)
setup_convert(MegaArgs A)
{
    __shared__ __align__(16) unsigned char smem[28032];
    int blk = blockIdx.x, tid = threadIdx.x;
    float* ws = A.ws;
    __bf16* w1b = (__bf16*)(ws + OFF_W1B);
    __bf16* w2b = (__bf16*)(ws + OFF_W2B);
    __bf16* wqb = (__bf16*)(ws + OFF_WQB);
    __bf16* wob = (__bf16*)(ws + OFF_WOB);
    if (blk == 1 && tid < BB * DD) A.out[tid] = 0.f;
    if (blk > 0) {
        for (int i = (blk - 1) * 256 + tid; i < NL*DFF*DD; i += 511 * 256) {
            w1b[i] = (__bf16)A.ff_w1[i];
            w2b[i] = (__bf16)A.ff_w2[i];
            if (i < NL*96*DD) wqb[i] = (__bf16)A.attn_in_w[i];
            if (i < NL*DD*DD) wob[i] = (__bf16)A.attn_out_w[i];
        }
        return;
    }
    setup_body(A.obs, A.mlp_w1, A.mlp_b1, A.mlp_w2, A.mlp_b2,
               A.mlp_w3, A.mlp_b3, A.mlp_w4, A.mlp_b4, ws, smem, tid);
}

__global__ void __launch_bounds__(64)
tokens_qkv(MegaArgs A)
{
    __shared__ float tab[128];
    __shared__ int apos[4];
    int l = threadIdx.x;
    int lo = l & 15, kg = l >> 4;
    float* ws = A.ws;
    tab[l] = ws[OFF_TABLE + l];
    tab[l + 64] = ws[OFF_TABLE + l + 64];
    if (l < 4) apos[l] = ((const int*)ws)[l];
    __syncthreads();
    tokens_job(A.obs, A.abs_emb, A.rel_w, A.rel_b, A.ang_w, A.ang_b,
               A.nbr_w, A.nbr_b, tab, apos, ws + OFF_X,
               (__bf16*)(ws + OFF_WQB), A.attn_in_b,
               (__bf16*)(ws + OFF_QB), (__bf16*)(ws + OFF_KB), (__bf16*)(ws + OFF_VT),
               blockIdx.x, lo, kg);
}

__global__ void __launch_bounds__(256)
attn_mfma(MegaArgs A)
{
    __shared__ __bf16 Pl[4][576];
    int tid = threadIdx.x;
    int w = tid >> 6, l = tid & 63, lo = l & 15, kg = l >> 4;
    float* ws = A.ws;
    attn_job((__bf16*)(ws + OFF_QB), (__bf16*)(ws + OFF_KB), (__bf16*)(ws + OFF_VT),
             ws + OFF_OP, ws + OFF_RS, &Pl[w][0], lo, kg, blockIdx.x * 4 + w);
}

template<int LAST>
__global__ void __launch_bounds__(256)
fused_layer(MegaArgs A)
{
    __shared__ __align__(16) unsigned char smem[28032];
    int tid = threadIdx.x;
    int w = tid >> 6, l = tid & 63, lo = l & 15, kg = l >> 4;
    float* ws = A.ws;
    size_t lofs = LAST ? 1 : 0;
    layer_tail(smem, ws + OFF_X, ws + OFF_OP, ws + OFF_RS,
        (__bf16*)(ws + OFF_WOB) + lofs * DD * DD, A.attn_out_b + lofs * DD,
        A.ln1_g + lofs * DD, A.ln1_b + lofs * DD,
        (__bf16*)(ws + OFF_W1B) + lofs * DFF * DD, A.ff_b1 + lofs * DFF,
        (__bf16*)(ws + OFF_W2B) + lofs * DD * DFF, A.ff_b2 + lofs * DD,
        A.ln2_g + lofs * DD, A.ln2_b + lofs * DD,
        (__bf16*)(ws + OFF_WQB) + (LAST ? 0 : (size_t)96 * DD),
        A.attn_in_b + (LAST ? 0 : 96),
        (__bf16*)(ws + OFF_QB), (__bf16*)(ws + OFF_KB), (__bf16*)(ws + OFF_VT),
        A.out, LAST, blockIdx.x * 16, w, l, lo, kg);
}

// ================= launch
extern "C" void kernel_launch(void* const* d_in, const int* in_sizes, int n_in,
                              void* d_out, int out_size, void* d_ws, size_t ws_size,
                              hipStream_t stream) {
    MegaArgs A;
    A.obs        = (const float*)d_in[0];
    A.mlp_w1     = (const float*)d_in[1];
    A.mlp_b1     = (const float*)d_in[2];
    A.mlp_w2     = (const float*)d_in[3];
    A.mlp_b2     = (const float*)d_in[4];
    A.mlp_w3     = (const float*)d_in[5];
    A.mlp_b3     = (const float*)d_in[6];
    A.mlp_w4     = (const float*)d_in[7];
    A.mlp_b4     = (const float*)d_in[8];
    A.abs_emb    = (const float*)d_in[9];
    A.rel_w      = (const float*)d_in[10];
    A.rel_b      = (const float*)d_in[11];
    A.ang_w      = (const float*)d_in[12];
    A.ang_b      = (const float*)d_in[13];
    A.nbr_w      = (const float*)d_in[14];
    A.nbr_b      = (const float*)d_in[15];
    A.attn_in_w  = (const float*)d_in[16];
    A.attn_in_b  = (const float*)d_in[17];
    A.attn_out_w = (const float*)d_in[18];
    A.attn_out_b = (const float*)d_in[19];
    A.ff_w1      = (const float*)d_in[20];
    A.ff_b1      = (const float*)d_in[21];
    A.ff_w2      = (const float*)d_in[22];
    A.ff_b2      = (const float*)d_in[23];
    A.ln1_g      = (const float*)d_in[24];
    A.ln1_b      = (const float*)d_in[25];
    A.ln2_g      = (const float*)d_in[26];
    A.ln2_b      = (const float*)d_in[27];
    A.ws         = (float*)d_ws;
    A.out        = (float*)d_out;

    void* kargs[] = { (void*)&A };
    hipError_t err = hipLaunchCooperativeKernel((const void*)mega, dim3(CBLK),
                                                dim3(256), kargs, 0, stream);
    if (err != hipSuccess) {
        (void)hipGetLastError();   // clear sticky error, use proven path
        setup_convert<<<512, 256, 0, stream>>>(A);
        tokens_qkv<<<NTB, 64, 0, stream>>>(A);
        attn_mfma<<<JOBS/4, 256, 0, stream>>>(A);
        fused_layer<0><<<NTB, 256, 0, stream>>>(A);
        attn_mfma<<<JOBS/4, 256, 0, stream>>>(A);
        fused_layer<1><<<NTB, 256, 0, stream>>>(A);
    }
}

// Round 17
// 127.746 us; speedup vs baseline: 3.6685x; 3.6685x over previous
//
#include <hip/hip_runtime.h>
#include <hip/hip_bf16.h>
#include <math.h>

#define SZ 48
#define NC 2304          // SIZE*SIZE
#define BB 4
#define DD 32
#define NH 4
#define HD 8
#define NL 2
#define DFF 2048
#define KSP 2            // attention k-splits (best; KSP=4 hurt twice)
#define NQB (NC/16)      // 144 query blocks per (b,h)
#define JOBS (BB*NH*NQB*KSP)   // 4608 wave-jobs

// Q pre-scale: (1/sqrt(8)) * log2(e) -> scores in log2 domain, use raw v_exp
#define QSCALE 0.51011784f

// ws layout in floats
#define OFF_TABLE 16
#define OFF_X   256
#define OFF_QB  (OFF_X   + BB*NC*DD)          // bf16 Q (pre-scaled)
#define OFF_KB  (OFF_QB  + (BB*NC*DD)/2)
#define OFF_VT  (OFF_KB  + (BB*NC*DD)/2)      // bf16 V transposed [bh][d][key]
#define OFF_OP  (OFF_VT  + (BB*NC*DD)/2)      // f32 partial O: JOBS*128
#define OFF_RS  (OFF_OP  + JOBS*128)          // f32 partial rsum: JOBS*16
#define OFF_W1B (OFF_RS  + JOBS*16)
#define OFF_W2B (OFF_W1B + (NL*DFF*DD)/2)
#define OFF_WQB (OFF_W2B + (NL*DFF*DD)/2)     // bf16 attn_in_w
#define OFF_WOB (OFF_WQB + (NL*96*DD)/2)      // bf16 attn_out_w

typedef __bf16 bf16x8 __attribute__((ext_vector_type(8)));
typedef __bf16 bf16x4 __attribute__((ext_vector_type(4)));
typedef float f32x4 __attribute__((ext_vector_type(4)));

__device__ __forceinline__ float gelu_exact(float x) {
    return 0.5f * x * (1.0f + erff(x * 0.7071067811865476f));
}

// raw 2^x — scores are bounded, no denormal fixup needed
__device__ __forceinline__ float exp2_raw(float x) {
    float r;
    asm("v_exp_f32 %0, %1" : "=v"(r) : "v"(x));
    return r;
}

// ---------------------------------------------------------------- setup + weight convert + out zero
__global__ void __launch_bounds__(256)
setup_convert(const float* __restrict__ obs,
    const float* __restrict__ w1, const float* __restrict__ b1,
    const float* __restrict__ w2, const float* __restrict__ b2,
    const float* __restrict__ w3, const float* __restrict__ b3,
    const float* __restrict__ w4, const float* __restrict__ b4,
    const float* __restrict__ fw1, const float* __restrict__ fw2,
    const float* __restrict__ wq, const float* __restrict__ wo,
    float* __restrict__ ws,
    __bf16* __restrict__ w1b, __bf16* __restrict__ w2b,
    __bf16* __restrict__ wqb, __bf16* __restrict__ wob,
    float* __restrict__ out)
{
    int blk = blockIdx.x, tid = threadIdx.x;
    if (blk == 1 && tid < BB * DD) out[tid] = 0.f;   // zero accumulator for fused mean
    if (blk > 0) {
        for (int i = (blk - 1) * 256 + tid; i < NL*DFF*DD; i += 511 * 256) {
            w1b[i] = (__bf16)fw1[i];
            w2b[i] = (__bf16)fw2[i];
            if (i < NL*96*DD) wqb[i] = (__bf16)wq[i];
            if (i < NL*DD*DD) wob[i] = (__bf16)wo[i];
        }
        return;
    }
    __shared__ int s_agent;
    __shared__ float h1[8][64];
    __shared__ float h2[8][128];
    __shared__ float h3[8][64];
    if (tid == 0) s_agent = 0;
    __syncthreads();
    for (int n = tid; n < NC; n += 256)
        if (obs[n] > 0.5f) atomicMax(&s_agent, n);
    __syncthreads();
    int a = s_agent;
    if (tid < 4) {
        const int di[4] = {-1, 1, 0, 0};
        const int dj[4] = {0, 0, -1, 1};
        int ai = a / SZ, aj = a % SZ;
        int ni = ai + di[tid], nj = aj + dj[tid];
        bool inb = (ni >= 0) && (ni < SZ) && (nj >= 0) && (nj < SZ);
        int nic = min(max(ni, 0), SZ - 1), njc = min(max(nj, 0), SZ - 1);
        bool ok = inb && (obs[2 * NC + nic * SZ + njc] == 0.0f);
        int ti = ok ? nic : ai, tj = ok ? njc : aj;
        ((int*)ws)[tid] = ti * SZ + tj;
    }
    for (int it = 0; it < 2; ++it) {
        int idx = tid + it * 256;
        int c = idx >> 6, j = idx & 63;
        float in0 = (float)((c >> 2) & 1);
        float in1 = (float)((c >> 1) & 1);
        float in2 = (float)(c & 1);
        float v = b1[j] + w1[j*3+0]*in0 + w1[j*3+1]*in1 + w1[j*3+2]*in2;
        h1[c][j] = gelu_exact(v);
    }
    __syncthreads();
    for (int it = 0; it < 4; ++it) {
        int idx = tid + it * 256;
        int c = idx >> 7, j = idx & 127;
        float v = b2[j];
        for (int k = 0; k < 64; ++k) v += w2[j*64+k] * h1[c][k];
        h2[c][j] = gelu_exact(v);
    }
    __syncthreads();
    for (int it = 0; it < 2; ++it) {
        int idx = tid + it * 256;
        int c = idx >> 6, j = idx & 63;
        float v = b3[j];
        for (int k = 0; k < 128; ++k) v += w3[j*128+k] * h2[c][k];
        h3[c][j] = gelu_exact(v);
    }
    __syncthreads();
    if (tid < 128) {
        int c = tid >> 4, j = tid & 15;
        float v = b4[j];
        for (int k = 0; k < 64; ++k) v += w4[j*64+k] * h3[c][k];
        ws[OFF_TABLE + c*16 + j] = v;
    }
}

// ---------------------------------------------------------------- tokens + layer-0 qkv (1 wave / 16 tokens)
__global__ void __launch_bounds__(64)
tokens_qkv(const float* __restrict__ obs, const float* __restrict__ abs_emb,
    const float* __restrict__ rel_w, const float* __restrict__ rel_b,
    const float* __restrict__ ang_w, const float* __restrict__ ang_b,
    const float* __restrict__ nbr_w, const float* __restrict__ nbr_b,
    const float* __restrict__ ws, float* __restrict__ X,
    const __bf16* __restrict__ Wq, const float* __restrict__ qbias,
    __bf16* __restrict__ Qb, __bf16* __restrict__ Kb, __bf16* __restrict__ Vt)
{
    __shared__ float tab[128];
    __shared__ int apos[4];
    int l = threadIdx.x;
    int lo = l & 15, kg = l >> 4;
    tab[l] = ws[OFF_TABLE + l];
    tab[l + 64] = ws[OFF_TABLE + l + 64];
    if (l < 4) apos[l] = ((const int*)ws)[l];
    __syncthreads();

    int t0 = blockIdx.x * 16;
    int b = t0 / NC;
    int n = (t0 % NC) + lo;
    int ap = apos[b];
    const float* goal = obs + NC;
    const float* wall = obs + 2 * NC;
    int i = n / SZ, j = n % SZ;

    float val[8];
    if (kg < 2) {
        int c0 = ((n == ap) ? 4 : 0) | ((goal[n] > 0.5f) ? 2 : 0) | ((wall[n] > 0.5f) ? 1 : 0);
        #pragma unroll
        for (int c = 0; c < 8; ++c) val[c] = tab[c0*16 + kg*8 + c];
    } else if (kg == 2) {
        #pragma unroll
        for (int o = 0; o < 4; ++o) val[o] = abs_emb[n*4 + o];
        int ar = ap / SZ, ac = ap % SZ;
        const float scc = 2.0f / (SZ - 1);
        float dr = (float)(ar - i) * scc;
        float dc = (float)(ac - j) * scc;
        #pragma unroll
        for (int o = 0; o < 4; ++o)
            val[4 + o] = rel_b[o] + rel_w[o*2+0]*dr + rel_w[o*2+1]*dc;
    } else {
        int ar = ap / SZ, ac = ap % SZ;
        const float scc = 2.0f / (SZ - 1);
        float dr = (float)(ar - i) * scc;
        float dc = (float)(ac - j) * scc;
        float ang = atan2f(dc, dr);
        float sa = sinf(ang), ca = cosf(ang);
        #pragma unroll
        for (int o = 0; o < 4; ++o)
            val[o] = ang_b[o] + ang_w[o*2+0]*sa + ang_w[o*2+1]*ca;
        int nb[4];
        nb[0] = (i > 0)      ? n - SZ : n;
        nb[1] = (i < SZ - 1) ? n + SZ : n;
        nb[2] = (j > 0)      ? n - 1  : n;
        nb[3] = (j < SZ - 1) ? n + 1  : n;
        float navg[16];
        #pragma unroll
        for (int c = 0; c < 16; ++c) navg[c] = 0.f;
        #pragma unroll
        for (int q = 0; q < 4; ++q) {
            int m = nb[q];
            int cq = ((m == ap) ? 4 : 0) | ((goal[m] > 0.5f) ? 2 : 0) | ((wall[m] > 0.5f) ? 1 : 0);
            #pragma unroll
            for (int c = 0; c < 16; ++c) navg[c] += tab[cq*16 + c];
        }
        #pragma unroll
        for (int o = 0; o < 4; ++o) {
            float v = nbr_b[o];
            #pragma unroll
            for (int c = 0; c < 16; ++c) v += nbr_w[o*16 + c] * (navg[c] * 0.25f);
            val[4 + o] = v;
        }
    }
    bf16x8 a;
    #pragma unroll
    for (int jj = 0; jj < 8; ++jj) {
        X[(size_t)(t0 + lo) * DD + kg * 8 + jj] = val[jj];
        a[jj] = (__bf16)val[jj];
    }
    const f32x4 zero = {0, 0, 0, 0};
    f32x4 acc[6];
    #pragma unroll
    for (int nn = 0; nn < 6; ++nn) {
        bf16x8 bf = *reinterpret_cast<const bf16x8*>(Wq + (size_t)(nn * 16 + lo) * DD + kg * 8);
        acc[nn] = __builtin_amdgcn_mfma_f32_16x16x32_bf16(a, bf, zero, 0, 0, 0);
    }
    #pragma unroll
    for (int nn = 0; nn < 6; ++nn) {
        int o = nn * 16 + lo;
        float bi = qbias[o];
        int part = o >> 5, oo = o & 31;
        int h = oo >> 3, dd = oo & 7;
        size_t bh = (size_t)(b * NH + h);
        #pragma unroll
        for (int r = 0; r < 4; ++r) {
            int t = t0 + kg * 4 + r;
            int tn = t % NC;
            float s = acc[nn][r] + bi;
            if (part == 0)
                Qb[(bh * NC + tn) * HD + dd] = (__bf16)(s * QSCALE);
            else if (part == 1)
                Kb[(bh * NC + tn) * HD + dd] = (__bf16)s;
            else
                Vt[(bh * HD + dd) * NC + tn] = (__bf16)s;
        }
    }
}

// ---------------------------------------------------------------- attention via MFMA (R10 best structure + setprio)
// S^T = mfma(K, Q); exp'd P bounced through wave-private LDS (in-order DS
// pipe, no barriers); PV: A = P rows, B = V^T; B col 8 = ones -> rsum.
// 1-chunk K/V register prefetch; raw v_exp; setprio(1) around MFMA cluster.
__global__ void __launch_bounds__(256)
attn_mfma(const __bf16* __restrict__ Qb, const __bf16* __restrict__ Kb,
          const __bf16* __restrict__ Vt, float* __restrict__ Op,
          float* __restrict__ Rs)
{
    __shared__ __bf16 Pl[4][16 * 36];   // per-wave 16q x 32k, row stride 36
    int tid = threadIdx.x;
    int w = tid >> 6, l = tid & 63, lo = l & 15, kg = l >> 4;
    int job = blockIdx.x * 4 + w;
    int bh  = job / (NQB * KSP);
    int rem = job % (NQB * KSP);
    int qb = rem >> 1, ks = rem & 1;

    const f32x4 zero = {0, 0, 0, 0};
    bf16x8 qfrag = {};
    if (kg == 0)
        qfrag = *reinterpret_cast<const bf16x8*>(Qb + ((size_t)bh * NC + qb * 16 + lo) * HD);
    __bf16* pl = &Pl[w][0];
    int k0base = ks * (NC / KSP);
    bool klane = (kg == 0);
    bool vlane = (lo < 8);

    // lo==8 lanes carry the persistent ones column (rsum); others zero
    bf16x8 vinit = {};
    if (lo == 8) {
        #pragma unroll
        for (int jj = 0; jj < 8; ++jj) vinit[jj] = (__bf16)1.0f;
    }

    // prefetch chunk 0
    bf16x8 kf0 = {}, kf1 = {};
    bf16x8 vcur = vinit;
    if (klane) {
        kf0 = *reinterpret_cast<const bf16x8*>(Kb + ((size_t)bh * NC + k0base + lo) * HD);
        kf1 = *reinterpret_cast<const bf16x8*>(Kb + ((size_t)bh * NC + k0base + 16 + lo) * HD);
    }
    if (vlane)
        vcur = *reinterpret_cast<const bf16x8*>(Vt + ((size_t)bh * HD + lo) * NC + k0base + kg * 8);

    f32x4 acc = zero;
    const int NCH = (NC / KSP) / 32;   // 36
    for (int ch = 0; ch < NCH; ++ch) {
        bf16x8 kf0c = kf0, kf1c = kf1, vc = vcur;
        if (ch + 1 < NCH) {
            int k1 = k0base + (ch + 1) * 32;
            if (klane) {
                kf0 = *reinterpret_cast<const bf16x8*>(Kb + ((size_t)bh * NC + k1 + lo) * HD);
                kf1 = *reinterpret_cast<const bf16x8*>(Kb + ((size_t)bh * NC + k1 + 16 + lo) * HD);
            }
            if (vlane)
                vcur = *reinterpret_cast<const bf16x8*>(Vt + ((size_t)bh * HD + lo) * NC + k1 + kg * 8);
        }
        __builtin_amdgcn_s_setprio(1);
        f32x4 s0 = __builtin_amdgcn_mfma_f32_16x16x32_bf16(kf0c, qfrag, zero, 0, 0, 0);
        f32x4 s1 = __builtin_amdgcn_mfma_f32_16x16x32_bf16(kf1c, qfrag, zero, 0, 0, 0);
        bf16x4 p0, p1;
        #pragma unroll
        for (int r = 0; r < 4; ++r) p0[r] = (__bf16)exp2_raw(s0[r]);
        #pragma unroll
        for (int r = 0; r < 4; ++r) p1[r] = (__bf16)exp2_raw(s1[r]);
        *reinterpret_cast<bf16x4*>(pl + lo * 36 + kg * 4)      = p0;
        *reinterpret_cast<bf16x4*>(pl + lo * 36 + 16 + kg * 4) = p1;
        bf16x8 pa = *reinterpret_cast<const bf16x8*>(pl + lo * 36 + kg * 8);
        acc = __builtin_amdgcn_mfma_f32_16x16x32_bf16(pa, vc, acc, 0, 0, 0);
        __builtin_amdgcn_s_setprio(0);
    }
    // acc: row = q (kg*4+r), col = lo (d<8: O; d==8: rsum)
    if (lo < 8) {
        #pragma unroll
        for (int r = 0; r < 4; ++r)
            Op[(size_t)job * 128 + (kg * 4 + r) * 8 + lo] = acc[r];
    } else if (lo == 8) {
        #pragma unroll
        for (int r = 0; r < 4; ++r)
            Rs[(size_t)job * 16 + kg * 4 + r] = acc[r];
    }
}

// ---------------------------------------------------------------- fused layer tail (proj+LN1 -> FF -> LN2 -> qkv/mean)
template<int LAST>
__global__ void __launch_bounds__(256)
fused_layer(float* __restrict__ Xf,
    const float* __restrict__ Op, const float* __restrict__ Rs,
    const __bf16* __restrict__ Wo, const float* __restrict__ obias,
    const float* __restrict__ g1, const float* __restrict__ bg1,
    const __bf16* __restrict__ w1b, const float* __restrict__ fb1,
    const __bf16* __restrict__ w2b, const float* __restrict__ fb2,
    const float* __restrict__ g2, const float* __restrict__ bg2,
    const __bf16* __restrict__ Wqn, const float* __restrict__ qbn,
    __bf16* __restrict__ Qb, __bf16* __restrict__ Kb, __bf16* __restrict__ Vt,
    float* __restrict__ out)
{
    __shared__ __align__(16) __bf16 Xl[16 * 40];
    __shared__ __align__(16) __bf16 Hl[4][2][648];
    __shared__ __align__(16) float accred[4][64][16];
    int tid = threadIdx.x;
    int w = tid >> 6, l = tid & 63, lo = l & 15, kg = l >> 4;
    int t0 = blockIdx.x * 16;
    int b = t0 / NC, qb = (t0 % NC) >> 4;
    const f32x4 zero = {0, 0, 0, 0};

    float xr0[4], xr1[4];   // x' (LN1 out), wave 0 only
    if (w == 0) {
        int jb = ((b * NH + kg) * NQB + qb) * KSP;
        float rs = 0.f;
        float ov[8];
        #pragma unroll
        for (int jj = 0; jj < 8; ++jj) ov[jj] = 0.f;
        #pragma unroll
        for (int s = 0; s < KSP; ++s) {
            rs += Rs[(jb + s) * 16 + lo];
            const float* pp = Op + (size_t)(jb + s) * 128 + lo * 8;
            #pragma unroll
            for (int jj = 0; jj < 8; ++jj) ov[jj] += pp[jj];
        }
        float inv = 1.0f / rs;
        bf16x8 a;
        #pragma unroll
        for (int jj = 0; jj < 8; ++jj) a[jj] = (__bf16)(ov[jj] * inv);
        bf16x8 bf0 = *reinterpret_cast<const bf16x8*>(Wo + (size_t)lo * DD + kg * 8);
        bf16x8 bf1 = *reinterpret_cast<const bf16x8*>(Wo + (size_t)(16 + lo) * DD + kg * 8);
        f32x4 acc0 = __builtin_amdgcn_mfma_f32_16x16x32_bf16(a, bf0, zero, 0, 0, 0);
        f32x4 acc1 = __builtin_amdgcn_mfma_f32_16x16x32_bf16(a, bf1, zero, 0, 0, 0);
        float bi0 = obias[lo], bi1 = obias[16 + lo];
        float gg0 = g1[lo], gg1 = g1[16 + lo];
        float bb0 = bg1[lo], bb1 = bg1[16 + lo];
        #pragma unroll
        for (int r = 0; r < 4; ++r) {
            int t = t0 + kg * 4 + r;
            float y0 = Xf[(size_t)t * DD + lo]      + acc0[r] + bi0;
            float y1 = Xf[(size_t)t * DD + 16 + lo] + acc1[r] + bi1;
            float s = y0 + y1;
            s += __shfl_xor(s, 1, 16); s += __shfl_xor(s, 2, 16);
            s += __shfl_xor(s, 4, 16); s += __shfl_xor(s, 8, 16);
            float mu = s * (1.0f / DD);
            float d0 = y0 - mu, d1 = y1 - mu;
            float v = d0 * d0 + d1 * d1;
            v += __shfl_xor(v, 1, 16); v += __shfl_xor(v, 2, 16);
            v += __shfl_xor(v, 4, 16); v += __shfl_xor(v, 8, 16);
            float linv = 1.0f / sqrtf(v * (1.0f / DD) + 1e-5f);
            xr0[r] = d0 * linv * gg0 + bb0;
            xr1[r] = d1 * linv * gg1 + bb1;
            Xl[(kg * 4 + r) * 40 + lo]      = (__bf16)xr0[r];
            Xl[(kg * 4 + r) * 40 + 16 + lo] = (__bf16)xr1[r];
        }
    }
    __syncthreads();

    // FF: each wave handles DFF/4 = 512 f-dims
    bf16x8 a1 = *reinterpret_cast<const bf16x8*>(&Xl[lo * 40 + kg * 8]);
    f32x4 accA0 = zero, accA1 = zero, accB0 = zero, accB1 = zero;
    for (int cc = w * 512; cc < w * 512 + 512; cc += 64) {
        int cA = cc, cB = cc + 32;
        bf16x8 b1A0 = *reinterpret_cast<const bf16x8*>(w1b + (size_t)(cA + lo) * DD + kg*8);
        bf16x8 b1A1 = *reinterpret_cast<const bf16x8*>(w1b + (size_t)(cA + 16 + lo) * DD + kg*8);
        bf16x8 b1B0 = *reinterpret_cast<const bf16x8*>(w1b + (size_t)(cB + lo) * DD + kg*8);
        bf16x8 b1B1 = *reinterpret_cast<const bf16x8*>(w1b + (size_t)(cB + 16 + lo) * DD + kg*8);
        f32x4 c1A0 = __builtin_amdgcn_mfma_f32_16x16x32_bf16(a1, b1A0, zero, 0, 0, 0);
        f32x4 c1A1 = __builtin_amdgcn_mfma_f32_16x16x32_bf16(a1, b1A1, zero, 0, 0, 0);
        f32x4 c1B0 = __builtin_amdgcn_mfma_f32_16x16x32_bf16(a1, b1B0, zero, 0, 0, 0);
        f32x4 c1B1 = __builtin_amdgcn_mfma_f32_16x16x32_bf16(a1, b1B1, zero, 0, 0, 0);
        float bA0 = fb1[cA + lo], bA1 = fb1[cA + 16 + lo];
        float bB0 = fb1[cB + lo], bB1 = fb1[cB + 16 + lo];
        #pragma unroll
        for (int r = 0; r < 4; ++r) {
            int tok = kg * 4 + r;
            Hl[w][0][tok*40 + lo]      = (__bf16)fmaxf(c1A0[r] + bA0, 0.f);
            Hl[w][0][tok*40 + 16 + lo] = (__bf16)fmaxf(c1A1[r] + bA1, 0.f);
            Hl[w][1][tok*40 + lo]      = (__bf16)fmaxf(c1B0[r] + bB0, 0.f);
            Hl[w][1][tok*40 + 16 + lo] = (__bf16)fmaxf(c1B1[r] + bB1, 0.f);
        }
        bf16x8 a2A = *reinterpret_cast<const bf16x8*>(&Hl[w][0][lo*40 + kg*8]);
        bf16x8 a2B = *reinterpret_cast<const bf16x8*>(&Hl[w][1][lo*40 + kg*8]);
        bf16x8 b2A0 = *reinterpret_cast<const bf16x8*>(w2b + (size_t)lo * DFF + cA + kg*8);
        bf16x8 b2A1 = *reinterpret_cast<const bf16x8*>(w2b + (size_t)(16 + lo) * DFF + cA + kg*8);
        bf16x8 b2B0 = *reinterpret_cast<const bf16x8*>(w2b + (size_t)lo * DFF + cB + kg*8);
        bf16x8 b2B1 = *reinterpret_cast<const bf16x8*>(w2b + (size_t)(16 + lo) * DFF + cB + kg*8);
        accA0 = __builtin_amdgcn_mfma_f32_16x16x32_bf16(a2A, b2A0, accA0, 0, 0, 0);
        accA1 = __builtin_amdgcn_mfma_f32_16x16x32_bf16(a2A, b2A1, accA1, 0, 0, 0);
        accB0 = __builtin_amdgcn_mfma_f32_16x16x32_bf16(a2B, b2B0, accB0, 0, 0, 0);
        accB1 = __builtin_amdgcn_mfma_f32_16x16x32_bf16(a2B, b2B1, accB1, 0, 0, 0);
    }
    *reinterpret_cast<f32x4*>(&accred[w][l][0])  = accA0;
    *reinterpret_cast<f32x4*>(&accred[w][l][4])  = accA1;
    *reinterpret_cast<f32x4*>(&accred[w][l][8])  = accB0;
    *reinterpret_cast<f32x4*>(&accred[w][l][12]) = accB1;
    __syncthreads();
    if (w != 0) return;

    accA0 = zero; accA1 = zero; accB0 = zero; accB1 = zero;
    #pragma unroll
    for (int ww = 0; ww < 4; ++ww) {
        accA0 += *reinterpret_cast<const f32x4*>(&accred[ww][l][0]);
        accA1 += *reinterpret_cast<const f32x4*>(&accred[ww][l][4]);
        accB0 += *reinterpret_cast<const f32x4*>(&accred[ww][l][8]);
        accB1 += *reinterpret_cast<const f32x4*>(&accred[ww][l][12]);
    }

    float b2v0 = fb2[lo], b2v1 = fb2[16 + lo];
    float gg0 = g2[lo], gg1 = g2[16 + lo];
    float bb0 = bg2[lo], bb1 = bg2[16 + lo];
    float s0 = 0.f, s1 = 0.f;
    #pragma unroll
    for (int r = 0; r < 4; ++r) {
        int t = t0 + kg * 4 + r;
        float y0 = xr0[r] + accA0[r] + accB0[r] + b2v0;
        float y1 = xr1[r] + accA1[r] + accB1[r] + b2v1;
        float s = y0 + y1;
        s += __shfl_xor(s, 1, 16); s += __shfl_xor(s, 2, 16);
        s += __shfl_xor(s, 4, 16); s += __shfl_xor(s, 8, 16);
        float mu = s * (1.0f / DD);
        float d0 = y0 - mu, d1 = y1 - mu;
        float v = d0 * d0 + d1 * d1;
        v += __shfl_xor(v, 1, 16); v += __shfl_xor(v, 2, 16);
        v += __shfl_xor(v, 4, 16); v += __shfl_xor(v, 8, 16);
        float linv = 1.0f / sqrtf(v * (1.0f / DD) + 1e-5f);
        float o0 = d0 * linv * gg0 + bb0;
        float o1 = d1 * linv * gg1 + bb1;
        if (!LAST) {
            Xf[(size_t)t * DD + lo]      = o0;
            Xf[(size_t)t * DD + 16 + lo] = o1;
            Xl[(kg * 4 + r) * 40 + lo]      = (__bf16)o0;
            Xl[(kg * 4 + r) * 40 + 16 + lo] = (__bf16)o1;
        } else {
            s0 += o0;
            s1 += o1;
        }
    }

    if (!LAST) {
        bf16x8 a = *reinterpret_cast<const bf16x8*>(&Xl[lo * 40 + kg * 8]);
        f32x4 accq[6];
        #pragma unroll
        for (int nn = 0; nn < 6; ++nn) {
            bf16x8 bf = *reinterpret_cast<const bf16x8*>(Wqn + (size_t)(nn * 16 + lo) * DD + kg * 8);
            accq[nn] = __builtin_amdgcn_mfma_f32_16x16x32_bf16(a, bf, zero, 0, 0, 0);
        }
        #pragma unroll
        for (int nn = 0; nn < 6; ++nn) {
            int o = nn * 16 + lo;
            float bi = qbn[o];
            int part = o >> 5, oo = o & 31;
            int h = oo >> 3, dd = oo & 7;
            size_t bh = (size_t)(b * NH + h);
            #pragma unroll
            for (int r = 0; r < 4; ++r) {
                int t = t0 + kg * 4 + r;
                int tn = t % NC;
                float s = accq[nn][r] + bi;
                if (part == 0)
                    Qb[(bh * NC + tn) * HD + dd] = (__bf16)(s * QSCALE);
                else if (part == 1)
                    Kb[(bh * NC + tn) * HD + dd] = (__bf16)s;
                else
                    Vt[(bh * HD + dd) * NC + tn] = (__bf16)s;
            }
        }
    } else {
        s0 += __shfl_xor(s0, 16); s0 += __shfl_xor(s0, 32);
        s1 += __shfl_xor(s1, 16); s1 += __shfl_xor(s1, 32);
        if (l < 16) {
            atomicAdd(out + b * DD + lo,      s0 * (1.0f / NC));
            atomicAdd(out + b * DD + 16 + lo, s1 * (1.0f / NC));
        }
    }
}

// ---------------------------------------------------------------- launch
extern "C" void kernel_launch(void* const* d_in, const int* in_sizes, int n_in,
                              void* d_out, int out_size, void* d_ws, size_t ws_size,
                              hipStream_t stream) {
    const float* obs       = (const float*)d_in[0];
    const float* mlp_w1    = (const float*)d_in[1];
    const float* mlp_b1    = (const float*)d_in[2];
    const float* mlp_w2    = (const float*)d_in[3];
    const float* mlp_b2    = (const float*)d_in[4];
    const float* mlp_w3    = (const float*)d_in[5];
    const float* mlp_b3    = (const float*)d_in[6];
    const float* mlp_w4    = (const float*)d_in[7];
    const float* mlp_b4    = (const float*)d_in[8];
    const float* abs_emb   = (const float*)d_in[9];
    const float* rel_w     = (const float*)d_in[10];
    const float* rel_b     = (const float*)d_in[11];
    const float* ang_w     = (const float*)d_in[12];
    const float* ang_b     = (const float*)d_in[13];
    const float* nbr_w     = (const float*)d_in[14];
    const float* nbr_b     = (const float*)d_in[15];
    const float* attn_in_w = (const float*)d_in[16];
    const float* attn_in_b = (const float*)d_in[17];
    const float* attn_out_w= (const float*)d_in[18];
    const float* attn_out_b= (const float*)d_in[19];
    const float* ff_w1     = (const float*)d_in[20];
    const float* ff_b1     = (const float*)d_in[21];
    const float* ff_w2     = (const float*)d_in[22];
    const float* ff_b2     = (const float*)d_in[23];
    const float* ln1_g     = (const float*)d_in[24];
    const float* ln1_b     = (const float*)d_in[25];
    const float* ln2_g     = (const float*)d_in[26];
    const float* ln2_b     = (const float*)d_in[27];

    float* ws = (float*)d_ws;
    float* X  = ws + OFF_X;
    __bf16* Qb = (__bf16*)(ws + OFF_QB);
    __bf16* Kb = (__bf16*)(ws + OFF_KB);
    __bf16* Vt = (__bf16*)(ws + OFF_VT);
    float* Op = ws + OFF_OP;
    float* Rs = ws + OFF_RS;
    __bf16* w1b = (__bf16*)(ws + OFF_W1B);
    __bf16* w2b = (__bf16*)(ws + OFF_W2B);
    __bf16* wqb = (__bf16*)(ws + OFF_WQB);
    __bf16* wob = (__bf16*)(ws + OFF_WOB);
    float* out = (float*)d_out;

    setup_convert<<<512, 256, 0, stream>>>(obs,
        mlp_w1, mlp_b1, mlp_w2, mlp_b2, mlp_w3, mlp_b3, mlp_w4, mlp_b4,
        ff_w1, ff_w2, attn_in_w, attn_out_w,
        ws, w1b, w2b, wqb, wob, out);
    tokens_qkv<<<(BB*NC)/16, 64, 0, stream>>>(obs, abs_emb, rel_w, rel_b,
        ang_w, ang_b, nbr_w, nbr_b, ws, X,
        wqb, attn_in_b, Qb, Kb, Vt);

    attn_mfma<<<JOBS/4, 256, 0, stream>>>(Qb, Kb, Vt, Op, Rs);
    fused_layer<0><<<(BB*NC)/16, 256, 0, stream>>>(
        X, Op, Rs,
        wob, attn_out_b, ln1_g, ln1_b,
        w1b, ff_b1, w2b, ff_b2, ln2_g, ln2_b,
        wqb + (size_t)96*DD, attn_in_b + 96, Qb, Kb, Vt, out);

    attn_mfma<<<JOBS/4, 256, 0, stream>>>(Qb, Kb, Vt, Op, Rs);
    fused_layer<1><<<(BB*NC)/16, 256, 0, stream>>>(
        X, Op, Rs,
        wob + (size_t)DD*DD, attn_out_b + DD, ln1_g + DD, ln1_b + DD,
        w1b + (size_t)DFF*DD, ff_b1 + DFF, w2b + (size_t)DD*DFF, ff_b2 + DD,
        ln2_g + DD, ln2_b + DD,
        nullptr, nullptr, nullptr, nullptr, nullptr, out);
}